// Round 5
// baseline (296.757 us; speedup 1.0000x reference)
//
#include <hip/hip_runtime.h>

// ============================================================================
// R5 = attribution experiment. Kernels are byte-identical to R4.
// k_pipe is launched 3x (idempotent) so dur_us = transform + 3*pipe:
//   pipe = (dur_R5 - dur_R4) / 2,  transform = dur_R4 - pipe.
// ============================================================================

#define BB 4096   // batch
#define TT 512    // time steps
#define DD 32     // input dim
#define NL 10     // layers
#define PH 8      // phase length (half of the double-buffered ring)

static constexpr float L2E = 1.4426950408889634f;   // log2(e)

__device__ __forceinline__ float fexp2(float x) { return __builtin_amdgcn_exp2f(x); }
__device__ __forceinline__ float frcp(float x)  { return __builtin_amdgcn_rcpf(x); }

// row_shr:1 within each 16-lane row; row-lane 0 gets 0 (bound_ctrl).
__device__ __forceinline__ float dpp_shr1(float x) {
    int r = __builtin_amdgcn_update_dpp(0, __float_as_int(x), 0x111, 0xF, 0xF, true);
    return __int_as_float(r);
}

// ---------------------------------------------------------------------------
// Kernel A (unchanged): G0[b][t][k] = scale[k]*(W_ih0[k,:].x[b,t,:] + b0[k])
// ---------------------------------------------------------------------------
__global__ __launch_bounds__(256) void k_transform(
    const float* __restrict__ x, const float* __restrict__ Wih0,
    const float* __restrict__ b0, float* __restrict__ G0)
{
    __shared__ float w[132];
    int tid = threadIdx.x;
    if (tid < 128) w[tid] = Wih0[tid];
    if (tid < 4)   w[128 + tid] = b0[tid];
    __syncthreads();

    int n = blockIdx.x * 256 + tid;     // n = b*TT + t

    const float4* xp = (const float4*)(x + (size_t)n * DD);
    float a0 = w[128], a1 = w[129], a2 = w[130], a3 = w[131];
#pragma unroll
    for (int ch = 0; ch < 8; ch++) {
        float4 xv = xp[ch];
        const float* w0 = &w[0 * 32 + ch * 4];
        const float* w1 = &w[1 * 32 + ch * 4];
        const float* w2 = &w[2 * 32 + ch * 4];
        const float* w3 = &w[3 * 32 + ch * 4];
        a0 += xv.x * w0[0] + xv.y * w0[1] + xv.z * w0[2] + xv.w * w0[3];
        a1 += xv.x * w1[0] + xv.y * w1[1] + xv.z * w1[2] + xv.w * w1[3];
        a2 += xv.x * w2[0] + xv.y * w2[1] + xv.z * w2[2] + xv.w * w2[3];
        a3 += xv.x * w3[0] + xv.y * w3[1] + xv.z * w3[2] + xv.w * w3[3];
    }
    float4 o;
    o.x = -L2E * a0;
    o.y = -L2E * a1;
    o.z = -2.f * L2E * a2;
    o.w = -L2E * a3;
    ((float4*)G0)[n] = o;
}

// ---------------------------------------------------------------------------
// Kernel B (unchanged from R4): skewed pipeline, 4 chains/wave, DPP handoff.
// ---------------------------------------------------------------------------
__global__ __launch_bounds__(64) void k_pipe(
    const float* __restrict__ G0, const float* __restrict__ Whh0,
    const float* __restrict__ Wihr, const float* __restrict__ Whhr,
    const float* __restrict__ br, float* __restrict__ out)
{
    int lane = threadIdx.x & 63;
    int cidx = lane >> 4;
    int l = lane & 15;                     // 0..9 live, 10..15 junk (contained)
    int chain = blockIdx.x * 4 + cidx;

    const float sk0 = -L2E, sk1 = -L2E, sk2 = -2.f * L2E, sk3 = -L2E;
    bool isl0 = (l == 0), isl9 = (l == NL - 1);
    int li = (l >= 1 && l <= 9) ? (l - 1) : 0;

    float wi0 = 0, wi1 = 0, wi2 = 0, wi3 = 0;
    float wh0, wh1, wh2, wh3;
    float bb0 = 0, bb1 = 0, bb2 = 0, bb3 = 0;
    if (isl0) {
        wh0 = sk0 * Whh0[0]; wh1 = sk1 * Whh0[1];
        wh2 = sk2 * Whh0[2]; wh3 = sk3 * Whh0[3];
    } else {
        const float* pi = Wihr + li * 4;
        const float* ph = Whhr + li * 4;
        const float* pb = br   + li * 4;
        wi0 = sk0 * pi[0]; wi1 = sk1 * pi[1]; wi2 = sk2 * pi[2]; wi3 = sk3 * pi[3];
        wh0 = sk0 * ph[0]; wh1 = sk1 * ph[1]; wh2 = sk2 * ph[2]; wh3 = sk3 * ph[3];
        bb0 = sk0 * pb[0]; bb1 = sk1 * pb[1]; bb2 = sk2 * pb[2]; bb3 = sk3 * pb[3];
    }

    const float4* G0v = (const float4*)G0 + (size_t)chain * TT;
    float* outp = out + (size_t)chain * TT;

    const float c2  = 2.f * L2E;
    float h = 0.f, cs = 0.f;              // cs = -2*L2E*c
    float o0 = 0.f, o1 = 0.f, o2 = 0.f, o3 = 0.f;

    float4 bbv = make_float4(bb0, bb1, bb2, bb3);
    float4 A[PH], B[PH];
#pragma unroll
    for (int i = 0; i < PH; i++) { A[i] = bbv; B[i] = bbv; }
    if (isl0) {
#pragma unroll
        for (int i = 0; i < PH; i++) A[i] = G0v[i];
#pragma unroll
        for (int i = 0; i < PH; i++) B[i] = G0v[PH + i];
    }

    auto STEP = [&](float4 g, int s, int jm) {
        int t = s - l;
        bool active = (t >= 0) && (t < TT);

        float hin = dpp_shr1(h);                      // h_{l-1}(t)
        float u0 = fmaf(h, wh0, fmaf(hin, wi0, g.x));
        float u1 = fmaf(h, wh1, fmaf(hin, wi1, g.y));
        float u2 = fmaf(h, wh2, fmaf(hin, wi2, g.z));
        float u3 = fmaf(h, wh3, fmaf(hin, wi3, g.w));

        float E0 = fexp2(u0), E1 = fexp2(u1), E2 = fexp2(u2), E3 = fexp2(u3);
        float A0 = 1.f + E0, A1 = 1.f + E1, A2 = 1.f + E2, A3 = 1.f + E3;
        float q02  = frcp(A0 * A2);
        float num2 = fmaf(E2, c2, -c2);
        float term = num2 * q02;
        float r1   = frcp(A1);
        float csn  = fmaf(cs, r1, term);              // -2L2E*c_new
        csn = fminf(fmaxf(csn, -88.f), 88.f);
        float Ec  = fexp2(csn);
        float Ac  = 1.f + Ec;
        float qc3 = frcp(Ac * A3);
        float hn  = (1.f - Ec) * qc3;

        if (active) { cs = csn; h = hn; }

        if (jm == 1) o0 = hn;
        else if (jm == 2) o1 = hn;
        else if (jm == 3) o2 = hn;
        else o3 = hn;
        if (jm == 0 && s >= 12 && s <= 520 && isl9) {
            float4 v;
            v.x = 60.f * frcp(1.f + fexp2(-L2E * o0));
            v.y = 60.f * frcp(1.f + fexp2(-L2E * o1));
            v.z = 60.f * frcp(1.f + fexp2(-L2E * o2));
            v.w = 60.f * frcp(1.f + fexp2(-L2E * o3));
            *(float4*)(outp + (s - 12)) = v;
        }
    };

    for (int sb = 0; sb < 528; sb += 2 * PH) {
#pragma unroll
        for (int j = 0; j < PH; j++) STEP(A[j], sb + j, j & 3);
        if (isl0) {
#pragma unroll
            for (int i = 0; i < PH; i++) {
                int st = sb + 2 * PH + i;
                st = st < TT ? st : TT - 1;
                A[i] = G0v[st];
            }
        }
#pragma unroll
        for (int j = 0; j < PH; j++) STEP(B[j], sb + PH + j, j & 3);
        if (isl0) {
#pragma unroll
            for (int i = 0; i < PH; i++) {
                int st = sb + 3 * PH + i;
                st = st < TT ? st : TT - 1;
                B[i] = G0v[st];
            }
        }
    }
}

// ---------------------------------------------------------------------------
// Fallback (ws too small): one thread per chain, monolithic.
// ---------------------------------------------------------------------------
__device__ __forceinline__ void cell_up(float u0, float u1, float u2, float u3,
                                        float& h, float& c)
{
    float ig = frcp(1.f + fexp2(u0));
    float fg = frcp(1.f + fexp2(u1));
    float gg = fmaf(2.f, frcp(1.f + fexp2(u2)), -1.f);
    float og = frcp(1.f + fexp2(u3));
    float cn = fmaf(fg, c, ig * gg);
    float th = fmaf(2.f, frcp(1.f + fexp2(-2.f * L2E * cn)), -1.f);
    c = cn; h = og * th;
}

__global__ __launch_bounds__(256) void k_mono(
    const float* __restrict__ x, const float* __restrict__ Wih0,
    const float* __restrict__ Whh0, const float* __restrict__ b0,
    const float* __restrict__ Wihr, const float* __restrict__ Whhr,
    const float* __restrict__ br, float* __restrict__ out)
{
    __shared__ float w[132];
    int tid = threadIdx.x;
    if (tid < 128) {
        int g = tid >> 5;
        w[tid] = ((g == 2) ? (-2.f * L2E) : (-L2E)) * Wih0[tid];
    }
    if (tid < 4) w[128 + tid] = ((tid == 2) ? (-2.f * L2E) : (-L2E)) * b0[tid];
    __syncthreads();

    int b = blockIdx.x * 256 + tid;
    float wh0[4], wir[NL - 1][4], whr[NL - 1][4], brr[NL - 1][4];
#pragma unroll
    for (int k = 0; k < 4; k++)
        wh0[k] = ((k == 2) ? (-2.f * L2E) : (-L2E)) * Whh0[k];
#pragma unroll
    for (int ll = 0; ll < NL - 1; ll++)
#pragma unroll
        for (int k = 0; k < 4; k++) {
            float s = (k == 2) ? (-2.f * L2E) : (-L2E);
            wir[ll][k] = s * Wihr[ll * 4 + k];
            whr[ll][k] = s * Whhr[ll * 4 + k];
            brr[ll][k] = s * br[ll * 4 + k];
        }
    float hh[NL], cc[NL];
#pragma unroll
    for (int ll = 0; ll < NL; ll++) { hh[ll] = 0.f; cc[ll] = 0.f; }

    const float4* xb = (const float4*)(x + (size_t)b * TT * DD);
    for (int t = 0; t < TT; t++) {
        float a0 = w[128], a1 = w[129], a2 = w[130], a3 = w[131];
#pragma unroll
        for (int ch = 0; ch < 8; ch++) {
            float4 xv = xb[t * 8 + ch];
            a0 += xv.x * w[0 * 32 + ch * 4] + xv.y * w[0 * 32 + ch * 4 + 1] + xv.z * w[0 * 32 + ch * 4 + 2] + xv.w * w[0 * 32 + ch * 4 + 3];
            a1 += xv.x * w[1 * 32 + ch * 4] + xv.y * w[1 * 32 + ch * 4 + 1] + xv.z * w[1 * 32 + ch * 4 + 2] + xv.w * w[1 * 32 + ch * 4 + 3];
            a2 += xv.x * w[2 * 32 + ch * 4] + xv.y * w[2 * 32 + ch * 4 + 1] + xv.z * w[2 * 32 + ch * 4 + 2] + xv.w * w[2 * 32 + ch * 4 + 3];
            a3 += xv.x * w[3 * 32 + ch * 4] + xv.y * w[3 * 32 + ch * 4 + 1] + xv.z * w[3 * 32 + ch * 4 + 2] + xv.w * w[3 * 32 + ch * 4 + 3];
        }
        float u0 = fmaf(hh[0], wh0[0], a0);
        float u1 = fmaf(hh[0], wh0[1], a1);
        float u2 = fmaf(hh[0], wh0[2], a2);
        float u3 = fmaf(hh[0], wh0[3], a3);
        cell_up(u0, u1, u2, u3, hh[0], cc[0]);
        float hin = hh[0];
#pragma unroll
        for (int ll = 1; ll < NL; ll++) {
            float v0 = fmaf(hin, wir[ll - 1][0], fmaf(hh[ll], whr[ll - 1][0], brr[ll - 1][0]));
            float v1 = fmaf(hin, wir[ll - 1][1], fmaf(hh[ll], whr[ll - 1][1], brr[ll - 1][1]));
            float v2 = fmaf(hin, wir[ll - 1][2], fmaf(hh[ll], whr[ll - 1][2], brr[ll - 1][2]));
            float v3 = fmaf(hin, wir[ll - 1][3], fmaf(hh[ll], whr[ll - 1][3], brr[ll - 1][3]));
            cell_up(v0, v1, v2, v3, hh[ll], cc[ll]);
            hin = hh[ll];
        }
        out[(size_t)b * TT + t] = 60.f * frcp(1.f + fexp2(-L2E * hh[NL - 1]));
    }
}

extern "C" void kernel_launch(void* const* d_in, const int* in_sizes, int n_in,
                              void* d_out, int out_size, void* d_ws, size_t ws_size,
                              hipStream_t stream)
{
    const float* x    = (const float*)d_in[0];
    const float* Wih0 = (const float*)d_in[1];
    const float* Whh0 = (const float*)d_in[2];
    const float* b0   = (const float*)d_in[3];
    const float* Wihr = (const float*)d_in[4];
    const float* Whhr = (const float*)d_in[5];
    const float* br   = (const float*)d_in[6];
    float* out = (float*)d_out;

    const size_t g0_bytes = (size_t)TT * BB * 4 * sizeof(float);   // 32 MiB
    if (ws_size >= g0_bytes) {
        float* G0 = (float*)d_ws;
        k_transform<<<(BB * TT) / 256, 256, 0, stream>>>(x, Wih0, b0, G0);
        // --- attribution: 3 idempotent launches; pipe = (dur_R5-dur_R4)/2 ---
        k_pipe<<<BB / 4, 64, 0, stream>>>(G0, Whh0, Wihr, Whhr, br, out);
        k_pipe<<<BB / 4, 64, 0, stream>>>(G0, Whh0, Wihr, Whhr, br, out);
        k_pipe<<<BB / 4, 64, 0, stream>>>(G0, Whh0, Wihr, Whhr, br, out);
    } else {
        k_mono<<<BB / 256, 256, 0, stream>>>(x, Wih0, Whh0, b0, Wihr, Whhr, br, out);
    }
}

// Round 6
// 184.951 us; speedup vs baseline: 1.6045x; 1.6045x over previous
//
#include <hip/hip_runtime.h>

#define BB 4096   // batch
#define TT 512    // time steps
#define DD 32     // input dim
#define NL 10     // layers
#define PH 8      // phase length (half of the double-buffered ring)

static constexpr float L2E = 1.4426950408889634f;   // log2(e)

__device__ __forceinline__ float fexp2(float x) { return __builtin_amdgcn_exp2f(x); }
__device__ __forceinline__ float frcp(float x)  { return __builtin_amdgcn_rcpf(x); }

// row_shr:1 within each 16-lane row; row-lane 0 gets 0 (bound_ctrl).
__device__ __forceinline__ float dpp_shr1(float x) {
    int r = __builtin_amdgcn_update_dpp(0, __float_as_int(x), 0x111, 0xF, 0xF, true);
    return __int_as_float(r);
}

// ---------------------------------------------------------------------------
// Kernel A v2: 8 lanes cooperate per row. Thread = one float4 chunk of x
// (lane i -> consecutive 16B: perfect coalescing). 16 FMA of partials, then
// 3-level shfl_xor butterfly within the 8-lane group; group leader adds bias,
// scales {-L2E,-L2E,-2L2E,-L2E}, writes G0[b][t] (8 leaders/wave -> 128B).
// ---------------------------------------------------------------------------
__global__ __launch_bounds__(256) void k_transform(
    const float* __restrict__ x, const float* __restrict__ Wih0,
    const float* __restrict__ b0, float* __restrict__ G0)
{
    __shared__ float4 wv[33];           // 32 = W_ih0 (4 gates x 8 chunks), [32]=bias
    float* w = (float*)wv;
    int tid = threadIdx.x;
    if (tid < 128) w[tid] = Wih0[tid];
    if (tid < 4)   w[128 + tid] = b0[tid];
    __syncthreads();

    int q = blockIdx.x * 256 + tid;     // global float4-chunk index
    int ch = tid & 7;                   // chunk within row (same as q&7)

    float4 xv = ((const float4*)x)[q];
    float4 w0 = wv[0 * 8 + ch];
    float4 w1 = wv[1 * 8 + ch];
    float4 w2 = wv[2 * 8 + ch];
    float4 w3 = wv[3 * 8 + ch];

    float p0 = xv.x * w0.x + xv.y * w0.y + xv.z * w0.z + xv.w * w0.w;
    float p1 = xv.x * w1.x + xv.y * w1.y + xv.z * w1.z + xv.w * w1.w;
    float p2 = xv.x * w2.x + xv.y * w2.y + xv.z * w2.z + xv.w * w2.w;
    float p3 = xv.x * w3.x + xv.y * w3.y + xv.z * w3.z + xv.w * w3.w;

#pragma unroll
    for (int m = 1; m <= 4; m <<= 1) {
        p0 += __shfl_xor(p0, m);
        p1 += __shfl_xor(p1, m);
        p2 += __shfl_xor(p2, m);
        p3 += __shfl_xor(p3, m);
    }

    if (ch == 0) {
        float4 o;
        o.x = -L2E * (p0 + w[128]);
        o.y = -L2E * (p1 + w[129]);
        o.z = -2.f * L2E * (p2 + w[130]);
        o.w = -L2E * (p3 + w[131]);
        ((float4*)G0)[q >> 3] = o;
    }
}

// ---------------------------------------------------------------------------
// Kernel B (unchanged from R4): skewed pipeline, 4 chains/wave, DPP handoff.
// ---------------------------------------------------------------------------
__global__ __launch_bounds__(64) void k_pipe(
    const float* __restrict__ G0, const float* __restrict__ Whh0,
    const float* __restrict__ Wihr, const float* __restrict__ Whhr,
    const float* __restrict__ br, float* __restrict__ out)
{
    int lane = threadIdx.x & 63;
    int cidx = lane >> 4;
    int l = lane & 15;                     // 0..9 live, 10..15 junk (contained)
    int chain = blockIdx.x * 4 + cidx;

    const float sk0 = -L2E, sk1 = -L2E, sk2 = -2.f * L2E, sk3 = -L2E;
    bool isl0 = (l == 0), isl9 = (l == NL - 1);
    int li = (l >= 1 && l <= 9) ? (l - 1) : 0;

    float wi0 = 0, wi1 = 0, wi2 = 0, wi3 = 0;
    float wh0, wh1, wh2, wh3;
    float bb0 = 0, bb1 = 0, bb2 = 0, bb3 = 0;
    if (isl0) {
        wh0 = sk0 * Whh0[0]; wh1 = sk1 * Whh0[1];
        wh2 = sk2 * Whh0[2]; wh3 = sk3 * Whh0[3];
    } else {
        const float* pi = Wihr + li * 4;
        const float* ph = Whhr + li * 4;
        const float* pb = br   + li * 4;
        wi0 = sk0 * pi[0]; wi1 = sk1 * pi[1]; wi2 = sk2 * pi[2]; wi3 = sk3 * pi[3];
        wh0 = sk0 * ph[0]; wh1 = sk1 * ph[1]; wh2 = sk2 * ph[2]; wh3 = sk3 * ph[3];
        bb0 = sk0 * pb[0]; bb1 = sk1 * pb[1]; bb2 = sk2 * pb[2]; bb3 = sk3 * pb[3];
    }

    const float4* G0v = (const float4*)G0 + (size_t)chain * TT;
    float* outp = out + (size_t)chain * TT;

    const float c2  = 2.f * L2E;
    float h = 0.f, cs = 0.f;              // cs = -2*L2E*c
    float o0 = 0.f, o1 = 0.f, o2 = 0.f, o3 = 0.f;

    float4 bbv = make_float4(bb0, bb1, bb2, bb3);
    float4 A[PH], B[PH];
#pragma unroll
    for (int i = 0; i < PH; i++) { A[i] = bbv; B[i] = bbv; }
    if (isl0) {
#pragma unroll
        for (int i = 0; i < PH; i++) A[i] = G0v[i];
#pragma unroll
        for (int i = 0; i < PH; i++) B[i] = G0v[PH + i];
    }

    auto STEP = [&](float4 g, int s, int jm) {
        int t = s - l;
        bool active = (t >= 0) && (t < TT);

        float hin = dpp_shr1(h);                      // h_{l-1}(t)
        float u0 = fmaf(h, wh0, fmaf(hin, wi0, g.x));
        float u1 = fmaf(h, wh1, fmaf(hin, wi1, g.y));
        float u2 = fmaf(h, wh2, fmaf(hin, wi2, g.z));
        float u3 = fmaf(h, wh3, fmaf(hin, wi3, g.w));

        float E0 = fexp2(u0), E1 = fexp2(u1), E2 = fexp2(u2), E3 = fexp2(u3);
        float A0 = 1.f + E0, A1 = 1.f + E1, A2 = 1.f + E2, A3 = 1.f + E3;
        float q02  = frcp(A0 * A2);
        float num2 = fmaf(E2, c2, -c2);
        float term = num2 * q02;
        float r1   = frcp(A1);
        float csn  = fmaf(cs, r1, term);              // -2L2E*c_new
        csn = fminf(fmaxf(csn, -88.f), 88.f);
        float Ec  = fexp2(csn);
        float Ac  = 1.f + Ec;
        float qc3 = frcp(Ac * A3);
        float hn  = (1.f - Ec) * qc3;

        if (active) { cs = csn; h = hn; }

        if (jm == 1) o0 = hn;
        else if (jm == 2) o1 = hn;
        else if (jm == 3) o2 = hn;
        else o3 = hn;
        if (jm == 0 && s >= 12 && s <= 520 && isl9) {
            float4 v;
            v.x = 60.f * frcp(1.f + fexp2(-L2E * o0));
            v.y = 60.f * frcp(1.f + fexp2(-L2E * o1));
            v.z = 60.f * frcp(1.f + fexp2(-L2E * o2));
            v.w = 60.f * frcp(1.f + fexp2(-L2E * o3));
            *(float4*)(outp + (s - 12)) = v;
        }
    };

    for (int sb = 0; sb < 528; sb += 2 * PH) {
#pragma unroll
        for (int j = 0; j < PH; j++) STEP(A[j], sb + j, j & 3);
        if (isl0) {
#pragma unroll
            for (int i = 0; i < PH; i++) {
                int st = sb + 2 * PH + i;
                st = st < TT ? st : TT - 1;
                A[i] = G0v[st];
            }
        }
#pragma unroll
        for (int j = 0; j < PH; j++) STEP(B[j], sb + PH + j, j & 3);
        if (isl0) {
#pragma unroll
            for (int i = 0; i < PH; i++) {
                int st = sb + 3 * PH + i;
                st = st < TT ? st : TT - 1;
                B[i] = G0v[st];
            }
        }
    }
}

// ---------------------------------------------------------------------------
// Fallback (ws too small): one thread per chain, monolithic.
// ---------------------------------------------------------------------------
__device__ __forceinline__ void cell_up(float u0, float u1, float u2, float u3,
                                        float& h, float& c)
{
    float ig = frcp(1.f + fexp2(u0));
    float fg = frcp(1.f + fexp2(u1));
    float gg = fmaf(2.f, frcp(1.f + fexp2(u2)), -1.f);
    float og = frcp(1.f + fexp2(u3));
    float cn = fmaf(fg, c, ig * gg);
    float th = fmaf(2.f, frcp(1.f + fexp2(-2.f * L2E * cn)), -1.f);
    c = cn; h = og * th;
}

__global__ __launch_bounds__(256) void k_mono(
    const float* __restrict__ x, const float* __restrict__ Wih0,
    const float* __restrict__ Whh0, const float* __restrict__ b0,
    const float* __restrict__ Wihr, const float* __restrict__ Whhr,
    const float* __restrict__ br, float* __restrict__ out)
{
    __shared__ float w[132];
    int tid = threadIdx.x;
    if (tid < 128) {
        int g = tid >> 5;
        w[tid] = ((g == 2) ? (-2.f * L2E) : (-L2E)) * Wih0[tid];
    }
    if (tid < 4) w[128 + tid] = ((tid == 2) ? (-2.f * L2E) : (-L2E)) * b0[tid];
    __syncthreads();

    int b = blockIdx.x * 256 + tid;
    float wh0[4], wir[NL - 1][4], whr[NL - 1][4], brr[NL - 1][4];
#pragma unroll
    for (int k = 0; k < 4; k++)
        wh0[k] = ((k == 2) ? (-2.f * L2E) : (-L2E)) * Whh0[k];
#pragma unroll
    for (int ll = 0; ll < NL - 1; ll++)
#pragma unroll
        for (int k = 0; k < 4; k++) {
            float s = (k == 2) ? (-2.f * L2E) : (-L2E);
            wir[ll][k] = s * Wihr[ll * 4 + k];
            whr[ll][k] = s * Whhr[ll * 4 + k];
            brr[ll][k] = s * br[ll * 4 + k];
        }
    float hh[NL], cc[NL];
#pragma unroll
    for (int ll = 0; ll < NL; ll++) { hh[ll] = 0.f; cc[ll] = 0.f; }

    const float4* xb = (const float4*)(x + (size_t)b * TT * DD);
    for (int t = 0; t < TT; t++) {
        float a0 = w[128], a1 = w[129], a2 = w[130], a3 = w[131];
#pragma unroll
        for (int ch = 0; ch < 8; ch++) {
            float4 xv = xb[t * 8 + ch];
            a0 += xv.x * w[0 * 32 + ch * 4] + xv.y * w[0 * 32 + ch * 4 + 1] + xv.z * w[0 * 32 + ch * 4 + 2] + xv.w * w[0 * 32 + ch * 4 + 3];
            a1 += xv.x * w[1 * 32 + ch * 4] + xv.y * w[1 * 32 + ch * 4 + 1] + xv.z * w[1 * 32 + ch * 4 + 2] + xv.w * w[1 * 32 + ch * 4 + 3];
            a2 += xv.x * w[2 * 32 + ch * 4] + xv.y * w[2 * 32 + ch * 4 + 1] + xv.z * w[2 * 32 + ch * 4 + 2] + xv.w * w[2 * 32 + ch * 4 + 3];
            a3 += xv.x * w[3 * 32 + ch * 4] + xv.y * w[3 * 32 + ch * 4 + 1] + xv.z * w[3 * 32 + ch * 4 + 2] + xv.w * w[3 * 32 + ch * 4 + 3];
        }
        float u0 = fmaf(hh[0], wh0[0], a0);
        float u1 = fmaf(hh[0], wh0[1], a1);
        float u2 = fmaf(hh[0], wh0[2], a2);
        float u3 = fmaf(hh[0], wh0[3], a3);
        cell_up(u0, u1, u2, u3, hh[0], cc[0]);
        float hin = hh[0];
#pragma unroll
        for (int ll = 1; ll < NL; ll++) {
            float v0 = fmaf(hin, wir[ll - 1][0], fmaf(hh[ll], whr[ll - 1][0], brr[ll - 1][0]));
            float v1 = fmaf(hin, wir[ll - 1][1], fmaf(hh[ll], whr[ll - 1][1], brr[ll - 1][1]));
            float v2 = fmaf(hin, wir[ll - 1][2], fmaf(hh[ll], whr[ll - 1][2], brr[ll - 1][2]));
            float v3 = fmaf(hin, wir[ll - 1][3], fmaf(hh[ll], whr[ll - 1][3], brr[ll - 1][3]));
            cell_up(v0, v1, v2, v3, hh[ll], cc[ll]);
            hin = hh[ll];
        }
        out[(size_t)b * TT + t] = 60.f * frcp(1.f + fexp2(-L2E * hh[NL - 1]));
    }
}

extern "C" void kernel_launch(void* const* d_in, const int* in_sizes, int n_in,
                              void* d_out, int out_size, void* d_ws, size_t ws_size,
                              hipStream_t stream)
{
    const float* x    = (const float*)d_in[0];
    const float* Wih0 = (const float*)d_in[1];
    const float* Whh0 = (const float*)d_in[2];
    const float* b0   = (const float*)d_in[3];
    const float* Wihr = (const float*)d_in[4];
    const float* Whhr = (const float*)d_in[5];
    const float* br   = (const float*)d_in[6];
    float* out = (float*)d_out;

    const size_t g0_bytes = (size_t)TT * BB * 4 * sizeof(float);   // 32 MiB
    if (ws_size >= g0_bytes) {
        float* G0 = (float*)d_ws;
        // 16.7M float4-chunks, 8 lanes per (b,t) row
        k_transform<<<(BB * TT * 8) / 256, 256, 0, stream>>>(x, Wih0, b0, G0);
        k_pipe<<<BB / 4, 64, 0, stream>>>(G0, Whh0, Wihr, Whhr, br, out);
    } else {
        k_mono<<<BB / 256, 256, 0, stream>>>(x, Wih0, Whh0, b0, Wihr, Whhr, br, out);
    }
}

// Round 7
// 122.004 us; speedup vs baseline: 2.4324x; 1.5159x over previous
//
#include <hip/hip_runtime.h>

#define BB 4096   // batch
#define TT 512    // time steps
#define DD 32     // input dim
#define NL 10     // layers
#define PH 8      // phase length (half of the double-buffered ring)

static constexpr float L2E = 1.4426950408889634f;   // log2(e)

typedef float f4 __attribute__((ext_vector_type(4)));

__device__ __forceinline__ float fexp2(float x) { return __builtin_amdgcn_exp2f(x); }
__device__ __forceinline__ float frcp(float x)  { return __builtin_amdgcn_rcpf(x); }

// row_shr:1 within each 16-lane row; row-lane 0 gets 0 (bound_ctrl).
__device__ __forceinline__ float dpp_shr1(float x) {
    int r = __builtin_amdgcn_update_dpp(0, __float_as_int(x), 0x111, 0xF, 0xF, true);
    return __int_as_float(r);
}

// ---------------------------------------------------------------------------
// Kernel A v3: 8 lanes/row split (each 64B line consumed inside ONE
// instruction -> safe without L1), NON-TEMPORAL x loads (no L3 allocate ->
// no dirty-fill-line evictions), grid-stride 2048 blocks x 32 iters.
// ---------------------------------------------------------------------------
__global__ __launch_bounds__(256) void k_transform(
    const float* __restrict__ x, const float* __restrict__ Wih0,
    const float* __restrict__ b0, float* __restrict__ G0)
{
    __shared__ f4 wv[33];               // 32 = W_ih0 (4 gates x 8 chunks), +bias
    float* w = (float*)wv;
    int tid = threadIdx.x;
    if (tid < 128) w[tid] = Wih0[tid];
    if (tid < 4)   w[128 + tid] = b0[tid];
    __syncthreads();

    int ch = tid & 7;                   // chunk within row (== q & 7)
    f4 w0 = wv[0 * 8 + ch];
    f4 w1 = wv[1 * 8 + ch];
    f4 w2 = wv[2 * 8 + ch];
    f4 w3 = wv[3 * 8 + ch];
    float b0s = w[128], b1s = w[129], b2s = w[130], b3s = w[131];

    const f4* xv = (const f4*)x;
    for (int q = blockIdx.x * 256 + tid; q < BB * TT * 8; q += gridDim.x * 256) {
        f4 v = __builtin_nontemporal_load(xv + q);

        float p0 = v.x * w0.x + v.y * w0.y + v.z * w0.z + v.w * w0.w;
        float p1 = v.x * w1.x + v.y * w1.y + v.z * w1.z + v.w * w1.w;
        float p2 = v.x * w2.x + v.y * w2.y + v.z * w2.z + v.w * w2.w;
        float p3 = v.x * w3.x + v.y * w3.y + v.z * w3.z + v.w * w3.w;

#pragma unroll
        for (int m = 1; m <= 4; m <<= 1) {
            p0 += __shfl_xor(p0, m);
            p1 += __shfl_xor(p1, m);
            p2 += __shfl_xor(p2, m);
            p3 += __shfl_xor(p3, m);
        }

        if (ch == 0) {
            float4 o;
            o.x = -L2E * (p0 + b0s);
            o.y = -L2E * (p1 + b1s);
            o.z = -2.f * L2E * (p2 + b2s);
            o.w = -L2E * (p3 + b3s);
            ((float4*)G0)[q >> 3] = o;
        }
    }
}

// ---------------------------------------------------------------------------
// Kernel B (byte-identical to R4): skewed pipeline, 4 chains/wave, DPP handoff.
// ---------------------------------------------------------------------------
__global__ __launch_bounds__(64) void k_pipe(
    const float* __restrict__ G0, const float* __restrict__ Whh0,
    const float* __restrict__ Wihr, const float* __restrict__ Whhr,
    const float* __restrict__ br, float* __restrict__ out)
{
    int lane = threadIdx.x & 63;
    int cidx = lane >> 4;
    int l = lane & 15;                     // 0..9 live, 10..15 junk (contained)
    int chain = blockIdx.x * 4 + cidx;

    const float sk0 = -L2E, sk1 = -L2E, sk2 = -2.f * L2E, sk3 = -L2E;
    bool isl0 = (l == 0), isl9 = (l == NL - 1);
    int li = (l >= 1 && l <= 9) ? (l - 1) : 0;

    float wi0 = 0, wi1 = 0, wi2 = 0, wi3 = 0;
    float wh0, wh1, wh2, wh3;
    float bb0 = 0, bb1 = 0, bb2 = 0, bb3 = 0;
    if (isl0) {
        wh0 = sk0 * Whh0[0]; wh1 = sk1 * Whh0[1];
        wh2 = sk2 * Whh0[2]; wh3 = sk3 * Whh0[3];
    } else {
        const float* pi = Wihr + li * 4;
        const float* ph = Whhr + li * 4;
        const float* pb = br   + li * 4;
        wi0 = sk0 * pi[0]; wi1 = sk1 * pi[1]; wi2 = sk2 * pi[2]; wi3 = sk3 * pi[3];
        wh0 = sk0 * ph[0]; wh1 = sk1 * ph[1]; wh2 = sk2 * ph[2]; wh3 = sk3 * ph[3];
        bb0 = sk0 * pb[0]; bb1 = sk1 * pb[1]; bb2 = sk2 * pb[2]; bb3 = sk3 * pb[3];
    }

    const float4* G0v = (const float4*)G0 + (size_t)chain * TT;
    float* outp = out + (size_t)chain * TT;

    const float c2  = 2.f * L2E;
    float h = 0.f, cs = 0.f;              // cs = -2*L2E*c
    float o0 = 0.f, o1 = 0.f, o2 = 0.f, o3 = 0.f;

    float4 bbv = make_float4(bb0, bb1, bb2, bb3);
    float4 A[PH], B[PH];
#pragma unroll
    for (int i = 0; i < PH; i++) { A[i] = bbv; B[i] = bbv; }
    if (isl0) {
#pragma unroll
        for (int i = 0; i < PH; i++) A[i] = G0v[i];
#pragma unroll
        for (int i = 0; i < PH; i++) B[i] = G0v[PH + i];
    }

    auto STEP = [&](float4 g, int s, int jm) {
        int t = s - l;
        bool active = (t >= 0) && (t < TT);

        float hin = dpp_shr1(h);                      // h_{l-1}(t)
        float u0 = fmaf(h, wh0, fmaf(hin, wi0, g.x));
        float u1 = fmaf(h, wh1, fmaf(hin, wi1, g.y));
        float u2 = fmaf(h, wh2, fmaf(hin, wi2, g.z));
        float u3 = fmaf(h, wh3, fmaf(hin, wi3, g.w));

        float E0 = fexp2(u0), E1 = fexp2(u1), E2 = fexp2(u2), E3 = fexp2(u3);
        float A0 = 1.f + E0, A1 = 1.f + E1, A2 = 1.f + E2, A3 = 1.f + E3;
        float q02  = frcp(A0 * A2);
        float num2 = fmaf(E2, c2, -c2);
        float term = num2 * q02;
        float r1   = frcp(A1);
        float csn  = fmaf(cs, r1, term);              // -2L2E*c_new
        csn = fminf(fmaxf(csn, -88.f), 88.f);
        float Ec  = fexp2(csn);
        float Ac  = 1.f + Ec;
        float qc3 = frcp(Ac * A3);
        float hn  = (1.f - Ec) * qc3;

        if (active) { cs = csn; h = hn; }

        if (jm == 1) o0 = hn;
        else if (jm == 2) o1 = hn;
        else if (jm == 3) o2 = hn;
        else o3 = hn;
        if (jm == 0 && s >= 12 && s <= 520 && isl9) {
            float4 v;
            v.x = 60.f * frcp(1.f + fexp2(-L2E * o0));
            v.y = 60.f * frcp(1.f + fexp2(-L2E * o1));
            v.z = 60.f * frcp(1.f + fexp2(-L2E * o2));
            v.w = 60.f * frcp(1.f + fexp2(-L2E * o3));
            *(float4*)(outp + (s - 12)) = v;
        }
    };

    for (int sb = 0; sb < 528; sb += 2 * PH) {
#pragma unroll
        for (int j = 0; j < PH; j++) STEP(A[j], sb + j, j & 3);
        if (isl0) {
#pragma unroll
            for (int i = 0; i < PH; i++) {
                int st = sb + 2 * PH + i;
                st = st < TT ? st : TT - 1;
                A[i] = G0v[st];
            }
        }
#pragma unroll
        for (int j = 0; j < PH; j++) STEP(B[j], sb + PH + j, j & 3);
        if (isl0) {
#pragma unroll
            for (int i = 0; i < PH; i++) {
                int st = sb + 3 * PH + i;
                st = st < TT ? st : TT - 1;
                B[i] = G0v[st];
            }
        }
    }
}

// ---------------------------------------------------------------------------
// Fallback (ws too small): one thread per chain, monolithic.
// ---------------------------------------------------------------------------
__device__ __forceinline__ void cell_up(float u0, float u1, float u2, float u3,
                                        float& h, float& c)
{
    float ig = frcp(1.f + fexp2(u0));
    float fg = frcp(1.f + fexp2(u1));
    float gg = fmaf(2.f, frcp(1.f + fexp2(u2)), -1.f);
    float og = frcp(1.f + fexp2(u3));
    float cn = fmaf(fg, c, ig * gg);
    float th = fmaf(2.f, frcp(1.f + fexp2(-2.f * L2E * cn)), -1.f);
    c = cn; h = og * th;
}

__global__ __launch_bounds__(256) void k_mono(
    const float* __restrict__ x, const float* __restrict__ Wih0,
    const float* __restrict__ Whh0, const float* __restrict__ b0,
    const float* __restrict__ Wihr, const float* __restrict__ Whhr,
    const float* __restrict__ br, float* __restrict__ out)
{
    __shared__ float w[132];
    int tid = threadIdx.x;
    if (tid < 128) {
        int g = tid >> 5;
        w[tid] = ((g == 2) ? (-2.f * L2E) : (-L2E)) * Wih0[tid];
    }
    if (tid < 4) w[128 + tid] = ((tid == 2) ? (-2.f * L2E) : (-L2E)) * b0[tid];
    __syncthreads();

    int b = blockIdx.x * 256 + tid;
    float wh0[4], wir[NL - 1][4], whr[NL - 1][4], brr[NL - 1][4];
#pragma unroll
    for (int k = 0; k < 4; k++)
        wh0[k] = ((k == 2) ? (-2.f * L2E) : (-L2E)) * Whh0[k];
#pragma unroll
    for (int ll = 0; ll < NL - 1; ll++)
#pragma unroll
        for (int k = 0; k < 4; k++) {
            float s = (k == 2) ? (-2.f * L2E) : (-L2E);
            wir[ll][k] = s * Wihr[ll * 4 + k];
            whr[ll][k] = s * Whhr[ll * 4 + k];
            brr[ll][k] = s * br[ll * 4 + k];
        }
    float hh[NL], cc[NL];
#pragma unroll
    for (int ll = 0; ll < NL; ll++) { hh[ll] = 0.f; cc[ll] = 0.f; }

    const float4* xb = (const float4*)(x + (size_t)b * TT * DD);
    for (int t = 0; t < TT; t++) {
        float a0 = w[128], a1 = w[129], a2 = w[130], a3 = w[131];
#pragma unroll
        for (int ch = 0; ch < 8; ch++) {
            float4 xv = xb[t * 8 + ch];
            a0 += xv.x * w[0 * 32 + ch * 4] + xv.y * w[0 * 32 + ch * 4 + 1] + xv.z * w[0 * 32 + ch * 4 + 2] + xv.w * w[0 * 32 + ch * 4 + 3];
            a1 += xv.x * w[1 * 32 + ch * 4] + xv.y * w[1 * 32 + ch * 4 + 1] + xv.z * w[1 * 32 + ch * 4 + 2] + xv.w * w[1 * 32 + ch * 4 + 3];
            a2 += xv.x * w[2 * 32 + ch * 4] + xv.y * w[2 * 32 + ch * 4 + 1] + xv.z * w[2 * 32 + ch * 4 + 2] + xv.w * w[2 * 32 + ch * 4 + 3];
            a3 += xv.x * w[3 * 32 + ch * 4] + xv.y * w[3 * 32 + ch * 4 + 1] + xv.z * w[3 * 32 + ch * 4 + 2] + xv.w * w[3 * 32 + ch * 4 + 3];
        }
        float u0 = fmaf(hh[0], wh0[0], a0);
        float u1 = fmaf(hh[0], wh0[1], a1);
        float u2 = fmaf(hh[0], wh0[2], a2);
        float u3 = fmaf(hh[0], wh0[3], a3);
        cell_up(u0, u1, u2, u3, hh[0], cc[0]);
        float hin = hh[0];
#pragma unroll
        for (int ll = 1; ll < NL; ll++) {
            float v0 = fmaf(hin, wir[ll - 1][0], fmaf(hh[ll], whr[ll - 1][0], brr[ll - 1][0]));
            float v1 = fmaf(hin, wir[ll - 1][1], fmaf(hh[ll], whr[ll - 1][1], brr[ll - 1][1]));
            float v2 = fmaf(hin, wir[ll - 1][2], fmaf(hh[ll], whr[ll - 1][2], brr[ll - 1][2]));
            float v3 = fmaf(hin, wir[ll - 1][3], fmaf(hh[ll], whr[ll - 1][3], brr[ll - 1][3]));
            cell_up(v0, v1, v2, v3, hh[ll], cc[ll]);
            hin = hh[ll];
        }
        out[(size_t)b * TT + t] = 60.f * frcp(1.f + fexp2(-L2E * hh[NL - 1]));
    }
}

extern "C" void kernel_launch(void* const* d_in, const int* in_sizes, int n_in,
                              void* d_out, int out_size, void* d_ws, size_t ws_size,
                              hipStream_t stream)
{
    const float* x    = (const float*)d_in[0];
    const float* Wih0 = (const float*)d_in[1];
    const float* Whh0 = (const float*)d_in[2];
    const float* b0   = (const float*)d_in[3];
    const float* Wihr = (const float*)d_in[4];
    const float* Whhr = (const float*)d_in[5];
    const float* br   = (const float*)d_in[6];
    float* out = (float*)d_out;

    const size_t g0_bytes = (size_t)TT * BB * 4 * sizeof(float);   // 32 MiB
    if (ws_size >= g0_bytes) {
        float* G0 = (float*)d_ws;
        k_transform<<<2048, 256, 0, stream>>>(x, Wih0, b0, G0);
        k_pipe<<<BB / 4, 64, 0, stream>>>(G0, Whh0, Wihr, Whhr, br, out);
    } else {
        k_mono<<<BB / 256, 256, 0, stream>>>(x, Wih0, Whh0, b0, Wihr, Whhr, br, out);
    }
}